// Round 1
// baseline (669.987 us; speedup 1.0000x reference)
//
#include <hip/hip_runtime.h>
#include <cstdint>
#include <cstddef>

#define D_IN   256
#define D_OUT  128

struct Branch {
  const float* X;
  const int*   idx;
  const float* val;
  float* H;
  int*   counts;
  int*   ptr;      // n+1
  int*   cursor;   // n
  int*   bsum;     // 64
  int*   csr_col;  // ne
  float* csr_val;  // ne
  float* out;
};

// ---------------- GEMM: H = X @ W  (fp32, LDS-tiled) ----------------
// block 256 threads: 32 rows x 128 cols per block; each thread 4 rows x 4 cols
__global__ __launch_bounds__(256) void gemm_kernel(const float* __restrict__ W,
                                                   Branch b0, Branch b1, int n_rows) {
  Branch b = blockIdx.y ? b1 : b0;
  __shared__ float sW[64][128];  // 32 KB (K-chunk of W)
  __shared__ float sX[32][64];   // 8 KB  (rows x K-chunk)
  const int tid = threadIdx.x;
  const int c4  = (tid & 31) * 4;
  const int rg  = (tid >> 5) * 4;
  const int row0 = blockIdx.x * 32;

  float4 acc[4];
  #pragma unroll
  for (int i = 0; i < 4; ++i) acc[i] = make_float4(0.f, 0.f, 0.f, 0.f);

  for (int k0 = 0; k0 < D_IN; k0 += 64) {
    // stage W chunk: 64x128 floats = 2048 float4; 8 per thread, coalesced
    const float4* Wv  = (const float4*)(W + (size_t)k0 * D_OUT);
    float4* sWv = (float4*)&sW[0][0];
    #pragma unroll
    for (int i = 0; i < 8; ++i) sWv[i * 256 + tid] = Wv[i * 256 + tid];
    // stage X chunk: 32 rows x 64 k = 512 float4; 2 per thread
    float4* sXv = (float4*)&sX[0][0];
    #pragma unroll
    for (int i = 0; i < 2; ++i) {
      int f = i * 256 + tid;
      int r = f >> 4, kk = f & 15;
      int gr = row0 + r; if (gr > n_rows - 1) gr = n_rows - 1;
      sXv[f] = ((const float4*)(b.X + (size_t)gr * D_IN + k0))[kk];
    }
    __syncthreads();
    #pragma unroll 8
    for (int k = 0; k < 64; ++k) {
      float4 w = *(const float4*)&sW[k][c4];
      float x0 = sX[rg + 0][k];
      float x1 = sX[rg + 1][k];
      float x2 = sX[rg + 2][k];
      float x3 = sX[rg + 3][k];
      acc[0].x = fmaf(w.x, x0, acc[0].x); acc[0].y = fmaf(w.y, x0, acc[0].y);
      acc[0].z = fmaf(w.z, x0, acc[0].z); acc[0].w = fmaf(w.w, x0, acc[0].w);
      acc[1].x = fmaf(w.x, x1, acc[1].x); acc[1].y = fmaf(w.y, x1, acc[1].y);
      acc[1].z = fmaf(w.z, x1, acc[1].z); acc[1].w = fmaf(w.w, x1, acc[1].w);
      acc[2].x = fmaf(w.x, x2, acc[2].x); acc[2].y = fmaf(w.y, x2, acc[2].y);
      acc[2].z = fmaf(w.z, x2, acc[2].z); acc[2].w = fmaf(w.w, x2, acc[2].w);
      acc[3].x = fmaf(w.x, x3, acc[3].x); acc[3].y = fmaf(w.y, x3, acc[3].y);
      acc[3].z = fmaf(w.z, x3, acc[3].z); acc[3].w = fmaf(w.w, x3, acc[3].w);
    }
    __syncthreads();
  }
  #pragma unroll
  for (int i = 0; i < 4; ++i) {
    int r = row0 + rg + i;
    if (r < n_rows) *(float4*)&b.H[(size_t)r * D_OUT + c4] = acc[i];
  }
}

// ---------------- CSR build ----------------
__global__ void count_kernel(Branch b0, Branch b1, int ne) {
  Branch b = blockIdx.y ? b1 : b0;
  int e = blockIdx.x * 256 + threadIdx.x;
  if (e < ne) atomicAdd(&b.counts[b.idx[2 * e]], 1);
}

__global__ __launch_bounds__(1024) void scanA_kernel(Branch b0, Branch b1, int n) {
  Branch b = blockIdx.y ? b1 : b0;
  __shared__ int buf[1024];
  int tid = threadIdx.x;
  int i = blockIdx.x * 1024 + tid;
  int v = (i < n) ? b.counts[i] : 0;
  buf[tid] = v;
  __syncthreads();
  #pragma unroll
  for (int off = 1; off < 1024; off <<= 1) {
    int t = (tid >= off) ? buf[tid - off] : 0;
    __syncthreads();
    buf[tid] += t;
    __syncthreads();
  }
  if (i < n) b.ptr[i] = buf[tid] - v;  // exclusive within block
  if (tid == 1023) b.bsum[blockIdx.x] = buf[1023];
}

__global__ void scanB_kernel(Branch b0, Branch b1, int nblk, int n) {
  Branch b = blockIdx.y ? b1 : b0;
  int lane = threadIdx.x;  // 64 threads, 1 wave
  int orig = (lane < nblk) ? b.bsum[lane] : 0;
  int v = orig;
  #pragma unroll
  for (int off = 1; off < 64; off <<= 1) {
    int t = __shfl_up(v, off);
    if (lane >= off) v += t;
  }
  if (lane < nblk) b.bsum[lane] = v - orig;  // exclusive block offsets
  if (lane == 63) b.ptr[n] = v;              // total
}

__global__ __launch_bounds__(1024) void scanC_kernel(Branch b0, Branch b1, int n) {
  Branch b = blockIdx.y ? b1 : b0;
  int i = blockIdx.x * 1024 + threadIdx.x;
  if (i < n) {
    int p = b.ptr[i] + b.bsum[blockIdx.x];
    b.ptr[i] = p;
    b.cursor[i] = p;
  }
}

__global__ void fill_kernel(Branch b0, Branch b1, int ne) {
  Branch b = blockIdx.y ? b1 : b0;
  int e = blockIdx.x * 256 + threadIdx.x;
  if (e < ne) {
    int r = b.idx[2 * e];
    int c = b.idx[2 * e + 1];
    float v = b.val[e];
    int pos = atomicAdd(&b.cursor[r], 1);
    b.csr_col[pos] = c;
    b.csr_val[pos] = v;
  }
}

// ---------------- per-row gather + relu ----------------
// 32 threads per row (float4 over 128 cols), 8 rows per 256-thread block
__global__ __launch_bounds__(256) void gather_kernel(Branch b0, Branch b1, int n_rows) {
  Branch b = blockIdx.y ? b1 : b0;
  int row = blockIdx.x * 8 + (threadIdx.x >> 5);
  if (row >= n_rows) return;
  int c4 = (threadIdx.x & 31) * 4;
  int beg = b.ptr[row], end = b.ptr[row + 1];
  float4 acc = make_float4(0.f, 0.f, 0.f, 0.f);
  int e = beg;
  for (; e + 4 <= end; e += 4) {
    int   cA = b.csr_col[e + 0], cB = b.csr_col[e + 1];
    int   cC = b.csr_col[e + 2], cD = b.csr_col[e + 3];
    float vA = b.csr_val[e + 0], vB = b.csr_val[e + 1];
    float vC = b.csr_val[e + 2], vD = b.csr_val[e + 3];
    float4 hA = *(const float4*)&b.H[(size_t)cA * D_OUT + c4];
    float4 hB = *(const float4*)&b.H[(size_t)cB * D_OUT + c4];
    float4 hC = *(const float4*)&b.H[(size_t)cC * D_OUT + c4];
    float4 hD = *(const float4*)&b.H[(size_t)cD * D_OUT + c4];
    acc.x = fmaf(hA.x, vA, acc.x); acc.y = fmaf(hA.y, vA, acc.y);
    acc.z = fmaf(hA.z, vA, acc.z); acc.w = fmaf(hA.w, vA, acc.w);
    acc.x = fmaf(hB.x, vB, acc.x); acc.y = fmaf(hB.y, vB, acc.y);
    acc.z = fmaf(hB.z, vB, acc.z); acc.w = fmaf(hB.w, vB, acc.w);
    acc.x = fmaf(hC.x, vC, acc.x); acc.y = fmaf(hC.y, vC, acc.y);
    acc.z = fmaf(hC.z, vC, acc.z); acc.w = fmaf(hC.w, vC, acc.w);
    acc.x = fmaf(hD.x, vD, acc.x); acc.y = fmaf(hD.y, vD, acc.y);
    acc.z = fmaf(hD.z, vD, acc.z); acc.w = fmaf(hD.w, vD, acc.w);
  }
  for (; e < end; ++e) {
    int c = b.csr_col[e];
    float v = b.csr_val[e];
    float4 h = *(const float4*)&b.H[(size_t)c * D_OUT + c4];
    acc.x = fmaf(h.x, v, acc.x); acc.y = fmaf(h.y, v, acc.y);
    acc.z = fmaf(h.z, v, acc.z); acc.w = fmaf(h.w, v, acc.w);
  }
  float4 o;
  o.x = fmaxf(acc.x, 0.f); o.y = fmaxf(acc.y, 0.f);
  o.z = fmaxf(acc.z, 0.f); o.w = fmaxf(acc.w, 0.f);
  *(float4*)&b.out[(size_t)row * D_OUT + c4] = o;
}

extern "C" void kernel_launch(void* const* d_in, const int* in_sizes, int n_in,
                              void* d_out, int out_size, void* d_ws, size_t ws_size,
                              hipStream_t stream) {
  const float* inp_s = (const float*)d_in[0];
  const float* inp_t = (const float*)d_in[1];
  const int*   idx_s = (const int*)d_in[2];
  const float* val_s = (const float*)d_in[3];
  const int*   idx_t = (const int*)d_in[4];
  const float* val_t = (const float*)d_in[5];
  const float* W     = (const float*)d_in[6];
  float* out = (float*)d_out;

  const int n  = in_sizes[0] / D_IN;   // 50000
  const int ne = in_sizes[3];          // 1600000

  // ---- workspace layout ----
  char* p = (char*)d_ws;
  auto alloc = [&](size_t bytes) -> char* {
    char* r = p;
    p += (bytes + 255) & ~(size_t)255;
    return r;
  };
  float* H_s      = (float*)alloc((size_t)n * D_OUT * 4);
  float* H_t      = (float*)alloc((size_t)n * D_OUT * 4);
  int*   counts   = (int*)alloc((size_t)2 * n * 4);   // s then t, one memset
  int*   counts_s = counts;
  int*   counts_t = counts + n;
  int*   ptr_s    = (int*)alloc((size_t)(n + 1) * 4);
  int*   ptr_t    = (int*)alloc((size_t)(n + 1) * 4);
  int*   cursor_s = (int*)alloc((size_t)n * 4);
  int*   cursor_t = (int*)alloc((size_t)n * 4);
  int*   bsum_s   = (int*)alloc(64 * 4);
  int*   bsum_t   = (int*)alloc(64 * 4);
  int*   col_s    = (int*)alloc((size_t)ne * 4);
  int*   col_t    = (int*)alloc((size_t)ne * 4);
  float* cval_s   = (float*)alloc((size_t)ne * 4);
  float* cval_t   = (float*)alloc((size_t)ne * 4);

  Branch bs = { inp_s, idx_s, val_s, H_s, counts_s, ptr_s, cursor_s, bsum_s, col_s, cval_s, out };
  Branch bt = { inp_t, idx_t, val_t, H_t, counts_t, ptr_t, cursor_t, bsum_t, col_t, cval_t,
                out + (size_t)n * D_OUT };

  const int nblk = (n + 1023) / 1024;

  hipMemsetAsync(counts, 0, (size_t)2 * n * 4, stream);
  gemm_kernel<<<dim3((n + 31) / 32, 2), 256, 0, stream>>>(W, bs, bt, n);
  count_kernel<<<dim3((ne + 255) / 256, 2), 256, 0, stream>>>(bs, bt, ne);
  scanA_kernel<<<dim3(nblk, 2), 1024, 0, stream>>>(bs, bt, n);
  scanB_kernel<<<dim3(1, 2), 64, 0, stream>>>(bs, bt, nblk, n);
  scanC_kernel<<<dim3(nblk, 2), 1024, 0, stream>>>(bs, bt, n);
  fill_kernel<<<dim3((ne + 255) / 256, 2), 256, 0, stream>>>(bs, bt, ne);
  gather_kernel<<<dim3((n + 7) / 8, 2), 256, 0, stream>>>(bs, bt, n);
}

// Round 2
// 583.149 us; speedup vs baseline: 1.1489x; 1.1489x over previous
//
#include <hip/hip_runtime.h>
#include <cstdint>
#include <cstddef>

#define D_IN   256
#define D_OUT  128

struct Branch {
  const float* X;
  const int*   idx;
  const float* val;
  uint32_t* H;        // bf16x2 packed, 64 words per row
  int*   counts;
  int*   ptr;         // n+1
  int*   cursor;      // n
  int*   bsum;        // 64
  uint64_t* csr_kv;   // ne: low32=col, high32=val bits
  float* out;
};

__device__ inline uint32_t pack_bf16_2(float a, float b) {
  uint32_t ua = __float_as_uint(a);
  uint32_t ub = __float_as_uint(b);
  uint32_t ra = (ua + 0x7FFFu + ((ua >> 16) & 1u)) >> 16;   // RNE
  uint32_t rb = (ub + 0x7FFFu + ((ub >> 16) & 1u)) & 0xFFFF0000u;
  // rb: round then keep high16 in place
  rb = ((ub + 0x7FFFu + ((ub >> 16) & 1u)) >> 16) << 16;
  return (ra & 0xFFFFu) | rb;
}

// ---------------- GEMM: H = X @ W  (fp32 compute, bf16 store) ----------------
// block 256 threads: 32 rows x 128 cols per block; each thread 4 rows x 4 cols
__global__ __launch_bounds__(256) void gemm_kernel(const float* __restrict__ W,
                                                   Branch b0, Branch b1, int n_rows) {
  Branch b = blockIdx.y ? b1 : b0;
  __shared__ float sW[64][128];  // 32 KB
  __shared__ float sX[32][64];   // 8 KB
  const int tid = threadIdx.x;
  const int c4  = (tid & 31) * 4;
  const int rg  = (tid >> 5) * 4;
  const int row0 = blockIdx.x * 32;

  float4 acc[4];
  #pragma unroll
  for (int i = 0; i < 4; ++i) acc[i] = make_float4(0.f, 0.f, 0.f, 0.f);

  for (int k0 = 0; k0 < D_IN; k0 += 64) {
    const float4* Wv  = (const float4*)(W + (size_t)k0 * D_OUT);
    float4* sWv = (float4*)&sW[0][0];
    #pragma unroll
    for (int i = 0; i < 8; ++i) sWv[i * 256 + tid] = Wv[i * 256 + tid];
    float4* sXv = (float4*)&sX[0][0];
    #pragma unroll
    for (int i = 0; i < 2; ++i) {
      int f = i * 256 + tid;
      int r = f >> 4, kk = f & 15;
      int gr = row0 + r; if (gr > n_rows - 1) gr = n_rows - 1;
      sXv[f] = ((const float4*)(b.X + (size_t)gr * D_IN + k0))[kk];
    }
    __syncthreads();
    #pragma unroll 8
    for (int k = 0; k < 64; ++k) {
      float4 w = *(const float4*)&sW[k][c4];
      float x0 = sX[rg + 0][k];
      float x1 = sX[rg + 1][k];
      float x2 = sX[rg + 2][k];
      float x3 = sX[rg + 3][k];
      acc[0].x = fmaf(w.x, x0, acc[0].x); acc[0].y = fmaf(w.y, x0, acc[0].y);
      acc[0].z = fmaf(w.z, x0, acc[0].z); acc[0].w = fmaf(w.w, x0, acc[0].w);
      acc[1].x = fmaf(w.x, x1, acc[1].x); acc[1].y = fmaf(w.y, x1, acc[1].y);
      acc[1].z = fmaf(w.z, x1, acc[1].z); acc[1].w = fmaf(w.w, x1, acc[1].w);
      acc[2].x = fmaf(w.x, x2, acc[2].x); acc[2].y = fmaf(w.y, x2, acc[2].y);
      acc[2].z = fmaf(w.z, x2, acc[2].z); acc[2].w = fmaf(w.w, x2, acc[2].w);
      acc[3].x = fmaf(w.x, x3, acc[3].x); acc[3].y = fmaf(w.y, x3, acc[3].y);
      acc[3].z = fmaf(w.z, x3, acc[3].z); acc[3].w = fmaf(w.w, x3, acc[3].w);
    }
    __syncthreads();
  }
  #pragma unroll
  for (int i = 0; i < 4; ++i) {
    int r = row0 + rg + i;
    if (r < n_rows) {
      uint2 hp;
      hp.x = pack_bf16_2(acc[i].x, acc[i].y);
      hp.y = pack_bf16_2(acc[i].z, acc[i].w);
      *(uint2*)&b.H[(size_t)r * (D_OUT / 2) + (c4 >> 1)] = hp;
    }
  }
}

// ---------------- CSR build ----------------
__global__ void count_kernel(Branch b0, Branch b1, int ne) {
  Branch b = blockIdx.y ? b1 : b0;
  int e = blockIdx.x * 256 + threadIdx.x;
  if (e < ne) atomicAdd(&b.counts[b.idx[2 * e]], 1);
}

__global__ __launch_bounds__(1024) void scanA_kernel(Branch b0, Branch b1, int n) {
  Branch b = blockIdx.y ? b1 : b0;
  __shared__ int buf[1024];
  int tid = threadIdx.x;
  int i = blockIdx.x * 1024 + tid;
  int v = (i < n) ? b.counts[i] : 0;
  buf[tid] = v;
  __syncthreads();
  #pragma unroll
  for (int off = 1; off < 1024; off <<= 1) {
    int t = (tid >= off) ? buf[tid - off] : 0;
    __syncthreads();
    buf[tid] += t;
    __syncthreads();
  }
  if (i < n) b.ptr[i] = buf[tid] - v;
  if (tid == 1023) b.bsum[blockIdx.x] = buf[1023];
}

__global__ void scanB_kernel(Branch b0, Branch b1, int nblk, int n) {
  Branch b = blockIdx.y ? b1 : b0;
  int lane = threadIdx.x;
  int orig = (lane < nblk) ? b.bsum[lane] : 0;
  int v = orig;
  #pragma unroll
  for (int off = 1; off < 64; off <<= 1) {
    int t = __shfl_up(v, off);
    if (lane >= off) v += t;
  }
  if (lane < nblk) b.bsum[lane] = v - orig;
  if (lane == 63) b.ptr[n] = v;
}

__global__ __launch_bounds__(1024) void scanC_kernel(Branch b0, Branch b1, int n) {
  Branch b = blockIdx.y ? b1 : b0;
  int i = blockIdx.x * 1024 + threadIdx.x;
  if (i < n) {
    int p = b.ptr[i] + b.bsum[blockIdx.x];
    b.ptr[i] = p;
    b.cursor[i] = p;
  }
}

__global__ void fill_kernel(Branch b0, Branch b1, int ne) {
  Branch b = blockIdx.y ? b1 : b0;
  int e = blockIdx.x * 256 + threadIdx.x;
  if (e < ne) {
    int r = b.idx[2 * e];
    int c = b.idx[2 * e + 1];
    float v = b.val[e];
    int pos = atomicAdd(&b.cursor[r], 1);
    uint64_t kv = ((uint64_t)__float_as_uint(v) << 32) | (uint32_t)c;
    b.csr_kv[pos] = kv;
  }
}

// ---------------- per-row gather + relu ----------------
// 32 threads per row; each lane owns 4 cols (8B bf16 read per H row)
__global__ __launch_bounds__(256) void gather_kernel(Branch b0, Branch b1, int n_rows) {
  Branch b = blockIdx.y ? b1 : b0;
  int row = blockIdx.x * 8 + (threadIdx.x >> 5);
  if (row >= n_rows) return;
  int lane2 = (threadIdx.x & 31) * 2;   // uint32 offset within H row
  int beg = b.ptr[row], end = b.ptr[row + 1];
  float4 acc = make_float4(0.f, 0.f, 0.f, 0.f);

  auto fma_edge = [&](uint64_t kv) {
    int c = (int)(uint32_t)kv;
    float v = __uint_as_float((uint32_t)(kv >> 32));
    uint2 h = *(const uint2*)&b.H[(size_t)c * (D_OUT / 2) + lane2];
    float h0 = __uint_as_float(h.x << 16);
    float h1 = __uint_as_float(h.x & 0xFFFF0000u);
    float h2 = __uint_as_float(h.y << 16);
    float h3 = __uint_as_float(h.y & 0xFFFF0000u);
    acc.x = fmaf(h0, v, acc.x); acc.y = fmaf(h1, v, acc.y);
    acc.z = fmaf(h2, v, acc.z); acc.w = fmaf(h3, v, acc.w);
  };

  int e = beg;
  for (; e + 4 <= end; e += 4) {
    uint64_t kA = b.csr_kv[e + 0], kB = b.csr_kv[e + 1];
    uint64_t kC = b.csr_kv[e + 2], kD = b.csr_kv[e + 3];
    fma_edge(kA); fma_edge(kB); fma_edge(kC); fma_edge(kD);
  }
  for (; e < end; ++e) fma_edge(b.csr_kv[e]);

  float4 o;
  o.x = fmaxf(acc.x, 0.f); o.y = fmaxf(acc.y, 0.f);
  o.z = fmaxf(acc.z, 0.f); o.w = fmaxf(acc.w, 0.f);
  *(float4*)&b.out[(size_t)row * D_OUT + (threadIdx.x & 31) * 4] = o;
}

extern "C" void kernel_launch(void* const* d_in, const int* in_sizes, int n_in,
                              void* d_out, int out_size, void* d_ws, size_t ws_size,
                              hipStream_t stream) {
  const float* inp_s = (const float*)d_in[0];
  const float* inp_t = (const float*)d_in[1];
  const int*   idx_s = (const int*)d_in[2];
  const float* val_s = (const float*)d_in[3];
  const int*   idx_t = (const int*)d_in[4];
  const float* val_t = (const float*)d_in[5];
  const float* W     = (const float*)d_in[6];
  float* out = (float*)d_out;

  const int n  = in_sizes[0] / D_IN;   // 50000
  const int ne = in_sizes[3];          // 1600000

  char* p = (char*)d_ws;
  auto alloc = [&](size_t bytes) -> char* {
    char* r = p;
    p += (bytes + 255) & ~(size_t)255;
    return r;
  };
  uint32_t* H_s    = (uint32_t*)alloc((size_t)n * (D_OUT / 2) * 4);
  uint32_t* H_t    = (uint32_t*)alloc((size_t)n * (D_OUT / 2) * 4);
  int* counts      = (int*)alloc((size_t)2 * n * 4);
  int* counts_s    = counts;
  int* counts_t    = counts + n;
  int* ptr_s       = (int*)alloc((size_t)(n + 1) * 4);
  int* ptr_t       = (int*)alloc((size_t)(n + 1) * 4);
  int* cursor_s    = (int*)alloc((size_t)n * 4);
  int* cursor_t    = (int*)alloc((size_t)n * 4);
  int* bsum_s      = (int*)alloc(64 * 4);
  int* bsum_t      = (int*)alloc(64 * 4);
  uint64_t* kv_s   = (uint64_t*)alloc((size_t)ne * 8);
  uint64_t* kv_t   = (uint64_t*)alloc((size_t)ne * 8);

  Branch bs = { inp_s, idx_s, val_s, H_s, counts_s, ptr_s, cursor_s, bsum_s, kv_s, out };
  Branch bt = { inp_t, idx_t, val_t, H_t, counts_t, ptr_t, cursor_t, bsum_t, kv_t,
                out + (size_t)n * D_OUT };

  const int nblk = (n + 1023) / 1024;

  hipMemsetAsync(counts, 0, (size_t)2 * n * 4, stream);
  gemm_kernel<<<dim3((n + 31) / 32, 2), 256, 0, stream>>>(W, bs, bt, n);
  count_kernel<<<dim3((ne + 255) / 256, 2), 256, 0, stream>>>(bs, bt, ne);
  scanA_kernel<<<dim3(nblk, 2), 1024, 0, stream>>>(bs, bt, n);
  scanB_kernel<<<dim3(1, 2), 64, 0, stream>>>(bs, bt, nblk, n);
  scanC_kernel<<<dim3(nblk, 2), 1024, 0, stream>>>(bs, bt, n);
  fill_kernel<<<dim3((ne + 255) / 256, 2), 256, 0, stream>>>(bs, bt, ne);
  gather_kernel<<<dim3((n + 7) / 8, 2), 256, 0, stream>>>(bs, bt, n);
}

// Round 3
// 453.928 us; speedup vs baseline: 1.4760x; 1.2847x over previous
//
#include <hip/hip_runtime.h>
#include <cstdint>
#include <cstddef>

#define D_IN   256
#define D_OUT  128
#define NB_MAX 256   // row buckets = (n+255)>>8 ; n must be <= 65535 (row/col packed in 16 bits)

struct Branch {
  const float* X;
  const int*   idx;
  const float* val;
  uint32_t* H;        // bf16x2 packed, 64 words per row
  int*   counts;
  int*   ptr;         // n+1
  int*   cursor;      // n
  int*   bsum;        // 64
  int*   bucketCur;   // NB_MAX
  uint64_t* kv2;      // ne: bucket-grouped (val32 | row16 | col16)
  uint64_t* csr_kv;   // ne: low32=col, high32=val bits
  float* out;
};

__device__ inline uint32_t pack_bf16_2(float a, float b) {
  uint32_t ua = __float_as_uint(a);
  uint32_t ub = __float_as_uint(b);
  uint32_t ra = (ua + 0x7FFFu + ((ua >> 16) & 1u)) >> 16;   // RNE
  uint32_t rb = ((ub + 0x7FFFu + ((ub >> 16) & 1u)) >> 16) << 16;
  return (ra & 0xFFFFu) | rb;
}

// ---------------- GEMM: H = X @ W  (fp32 compute, bf16 store) ----------------
__global__ __launch_bounds__(256) void gemm_kernel(const float* __restrict__ W,
                                                   Branch b0, Branch b1, int n_rows) {
  Branch b = blockIdx.y ? b1 : b0;
  __shared__ float sW[64][128];
  __shared__ float sX[32][64];
  const int tid = threadIdx.x;
  const int c4  = (tid & 31) * 4;
  const int rg  = (tid >> 5) * 4;
  const int row0 = blockIdx.x * 32;

  float4 acc[4];
  #pragma unroll
  for (int i = 0; i < 4; ++i) acc[i] = make_float4(0.f, 0.f, 0.f, 0.f);

  for (int k0 = 0; k0 < D_IN; k0 += 64) {
    const float4* Wv  = (const float4*)(W + (size_t)k0 * D_OUT);
    float4* sWv = (float4*)&sW[0][0];
    #pragma unroll
    for (int i = 0; i < 8; ++i) sWv[i * 256 + tid] = Wv[i * 256 + tid];
    float4* sXv = (float4*)&sX[0][0];
    #pragma unroll
    for (int i = 0; i < 2; ++i) {
      int f = i * 256 + tid;
      int r = f >> 4, kk = f & 15;
      int gr = row0 + r; if (gr > n_rows - 1) gr = n_rows - 1;
      sXv[f] = ((const float4*)(b.X + (size_t)gr * D_IN + k0))[kk];
    }
    __syncthreads();
    #pragma unroll 8
    for (int k = 0; k < 64; ++k) {
      float4 w = *(const float4*)&sW[k][c4];
      float x0 = sX[rg + 0][k];
      float x1 = sX[rg + 1][k];
      float x2 = sX[rg + 2][k];
      float x3 = sX[rg + 3][k];
      acc[0].x = fmaf(w.x, x0, acc[0].x); acc[0].y = fmaf(w.y, x0, acc[0].y);
      acc[0].z = fmaf(w.z, x0, acc[0].z); acc[0].w = fmaf(w.w, x0, acc[0].w);
      acc[1].x = fmaf(w.x, x1, acc[1].x); acc[1].y = fmaf(w.y, x1, acc[1].y);
      acc[1].z = fmaf(w.z, x1, acc[1].z); acc[1].w = fmaf(w.w, x1, acc[1].w);
      acc[2].x = fmaf(w.x, x2, acc[2].x); acc[2].y = fmaf(w.y, x2, acc[2].y);
      acc[2].z = fmaf(w.z, x2, acc[2].z); acc[2].w = fmaf(w.w, x2, acc[2].w);
      acc[3].x = fmaf(w.x, x3, acc[3].x); acc[3].y = fmaf(w.y, x3, acc[3].y);
      acc[3].z = fmaf(w.z, x3, acc[3].z); acc[3].w = fmaf(w.w, x3, acc[3].w);
    }
    __syncthreads();
  }
  #pragma unroll
  for (int i = 0; i < 4; ++i) {
    int r = row0 + rg + i;
    if (r < n_rows) {
      uint2 hp;
      hp.x = pack_bf16_2(acc[i].x, acc[i].y);
      hp.y = pack_bf16_2(acc[i].z, acc[i].w);
      *(uint2*)&b.H[(size_t)r * (D_OUT / 2) + (c4 >> 1)] = hp;
    }
  }
}

// ---------------- CSR build ----------------
__global__ void count_kernel(Branch b0, Branch b1, int ne) {
  Branch b = blockIdx.y ? b1 : b0;
  int e = blockIdx.x * 256 + threadIdx.x;
  if (e < ne) atomicAdd(&b.counts[b.idx[2 * e]], 1);
}

__global__ __launch_bounds__(1024) void scanA_kernel(Branch b0, Branch b1, int n) {
  Branch b = blockIdx.y ? b1 : b0;
  __shared__ int buf[1024];
  int tid = threadIdx.x;
  int i = blockIdx.x * 1024 + tid;
  int v = (i < n) ? b.counts[i] : 0;
  buf[tid] = v;
  __syncthreads();
  #pragma unroll
  for (int off = 1; off < 1024; off <<= 1) {
    int t = (tid >= off) ? buf[tid - off] : 0;
    __syncthreads();
    buf[tid] += t;
    __syncthreads();
  }
  if (i < n) b.ptr[i] = buf[tid] - v;
  if (tid == 1023) b.bsum[blockIdx.x] = buf[1023];
}

__global__ void scanB_kernel(Branch b0, Branch b1, int nblk, int n) {
  Branch b = blockIdx.y ? b1 : b0;
  int lane = threadIdx.x;
  int orig = (lane < nblk) ? b.bsum[lane] : 0;
  int v = orig;
  #pragma unroll
  for (int off = 1; off < 64; off <<= 1) {
    int t = __shfl_up(v, off);
    if (lane >= off) v += t;
  }
  if (lane < nblk) b.bsum[lane] = v - orig;
  if (lane == 63) b.ptr[n] = v;
}

__global__ __launch_bounds__(1024) void scanC_kernel(Branch b0, Branch b1, int n) {
  Branch b = blockIdx.y ? b1 : b0;
  int i = blockIdx.x * 1024 + threadIdx.x;
  if (i < n) {
    int p = b.ptr[i] + b.bsum[blockIdx.x];
    b.ptr[i] = p;
    b.cursor[i] = p;
    if ((i & 255) == 0) b.bucketCur[i >> 8] = p;   // bucket start = ptr[b*256]
  }
}

// ---------------- two-level fill ----------------
// level 1: bucket-grouped scatter (row>>8), per-block LDS histogram + segment reservation
__global__ __launch_bounds__(256) void bin_kernel(Branch b0, Branch b1, int ne, int nb) {
  Branch b = blockIdx.y ? b1 : b0;
  __shared__ int hist[NB_MAX];
  __shared__ int lcur[NB_MAX];
  __shared__ int gbase[NB_MAX];
  const int tid = threadIdx.x;
  const int base = blockIdx.x * 4096;
  if (tid < nb) hist[tid] = 0;
  __syncthreads();
  uint64_t kv2[16];
  int bkt[16];
  #pragma unroll
  for (int i = 0; i < 16; ++i) {
    int e = base + i * 256 + tid;
    bkt[i] = -1;
    if (e < ne) {
      int2 rc = ((const int2*)b.idx)[e];
      uint32_t v = __float_as_uint(b.val[e]);
      kv2[i] = ((uint64_t)v << 32) | ((uint32_t)rc.x << 16) | (uint32_t)rc.y;
      bkt[i] = rc.x >> 8;
      atomicAdd(&hist[bkt[i]], 1);
    }
  }
  __syncthreads();
  if (tid < nb) {
    int h = hist[tid];
    gbase[tid] = h ? atomicAdd(&b.bucketCur[tid], h) : 0;
    lcur[tid] = 0;
  }
  __syncthreads();
  #pragma unroll
  for (int i = 0; i < 16; ++i) {
    if (bkt[i] >= 0) {
      int dst = gbase[bkt[i]] + atomicAdd(&lcur[bkt[i]], 1);
      b.kv2[dst] = kv2[i];
    }
  }
}

// level 2: exact CSR position; scatter stays inside the (L2-hot) bucket range
__global__ __launch_bounds__(256) void fill2_kernel(Branch b0, Branch b1, int ne) {
  Branch b = blockIdx.y ? b1 : b0;
  const int tid = threadIdx.x;
  const int base = blockIdx.x * 4096;
  #pragma unroll
  for (int i = 0; i < 16; ++i) {
    int e = base + i * 256 + tid;
    if (e < ne) {
      uint64_t kv2 = b.kv2[e];
      int row = (int)((kv2 >> 16) & 0xFFFFu);
      uint32_t col = (uint32_t)(kv2 & 0xFFFFu);
      int pos = atomicAdd(&b.cursor[row], 1);
      b.csr_kv[pos] = (kv2 & 0xFFFFFFFF00000000ULL) | col;
    }
  }
}

// ---------------- per-row gather + relu ----------------
__global__ __launch_bounds__(256) void gather_kernel(Branch b0, Branch b1, int n_rows) {
  Branch b = blockIdx.y ? b1 : b0;
  int row = blockIdx.x * 8 + (threadIdx.x >> 5);
  if (row >= n_rows) return;
  int lane2 = (threadIdx.x & 31) * 2;
  int beg = b.ptr[row], end = b.ptr[row + 1];
  float4 acc = make_float4(0.f, 0.f, 0.f, 0.f);

  auto fma_edge = [&](uint64_t kv) {
    int c = (int)(uint32_t)kv;
    float v = __uint_as_float((uint32_t)(kv >> 32));
    uint2 h = *(const uint2*)&b.H[(size_t)c * (D_OUT / 2) + lane2];
    float h0 = __uint_as_float(h.x << 16);
    float h1 = __uint_as_float(h.x & 0xFFFF0000u);
    float h2 = __uint_as_float(h.y << 16);
    float h3 = __uint_as_float(h.y & 0xFFFF0000u);
    acc.x = fmaf(h0, v, acc.x); acc.y = fmaf(h1, v, acc.y);
    acc.z = fmaf(h2, v, acc.z); acc.w = fmaf(h3, v, acc.w);
  };

  int e = beg;
  for (; e + 4 <= end; e += 4) {
    uint64_t kA = b.csr_kv[e + 0], kB = b.csr_kv[e + 1];
    uint64_t kC = b.csr_kv[e + 2], kD = b.csr_kv[e + 3];
    fma_edge(kA); fma_edge(kB); fma_edge(kC); fma_edge(kD);
  }
  for (; e < end; ++e) fma_edge(b.csr_kv[e]);

  float4 o;
  o.x = fmaxf(acc.x, 0.f); o.y = fmaxf(acc.y, 0.f);
  o.z = fmaxf(acc.z, 0.f); o.w = fmaxf(acc.w, 0.f);
  *(float4*)&b.out[(size_t)row * D_OUT + (threadIdx.x & 31) * 4] = o;
}

extern "C" void kernel_launch(void* const* d_in, const int* in_sizes, int n_in,
                              void* d_out, int out_size, void* d_ws, size_t ws_size,
                              hipStream_t stream) {
  const float* inp_s = (const float*)d_in[0];
  const float* inp_t = (const float*)d_in[1];
  const int*   idx_s = (const int*)d_in[2];
  const float* val_s = (const float*)d_in[3];
  const int*   idx_t = (const int*)d_in[4];
  const float* val_t = (const float*)d_in[5];
  const float* W     = (const float*)d_in[6];
  float* out = (float*)d_out;

  const int n  = in_sizes[0] / D_IN;   // 50000
  const int ne = in_sizes[3];          // 1600000
  const int nb = (n + 255) >> 8;       // 196

  char* p = (char*)d_ws;
  auto alloc = [&](size_t bytes) -> char* {
    char* r = p;
    p += (bytes + 255) & ~(size_t)255;
    return r;
  };
  uint32_t* H_s    = (uint32_t*)alloc((size_t)n * (D_OUT / 2) * 4);
  uint32_t* H_t    = (uint32_t*)alloc((size_t)n * (D_OUT / 2) * 4);
  int* counts      = (int*)alloc((size_t)2 * n * 4);
  int* counts_s    = counts;
  int* counts_t    = counts + n;
  int* ptr_s       = (int*)alloc((size_t)(n + 1) * 4);
  int* ptr_t       = (int*)alloc((size_t)(n + 1) * 4);
  int* cursor_s    = (int*)alloc((size_t)n * 4);
  int* cursor_t    = (int*)alloc((size_t)n * 4);
  int* bsum_s      = (int*)alloc(64 * 4);
  int* bsum_t      = (int*)alloc(64 * 4);
  int* bcur_s      = (int*)alloc(NB_MAX * 4);
  int* bcur_t      = (int*)alloc(NB_MAX * 4);
  uint64_t* kv2_s  = (uint64_t*)alloc((size_t)ne * 8);
  uint64_t* kv2_t  = (uint64_t*)alloc((size_t)ne * 8);
  uint64_t* kv_s   = (uint64_t*)alloc((size_t)ne * 8);
  uint64_t* kv_t   = (uint64_t*)alloc((size_t)ne * 8);

  Branch bs = { inp_s, idx_s, val_s, H_s, counts_s, ptr_s, cursor_s, bsum_s, bcur_s, kv2_s, kv_s, out };
  Branch bt = { inp_t, idx_t, val_t, H_t, counts_t, ptr_t, cursor_t, bsum_t, bcur_t, kv2_t, kv_t,
                out + (size_t)n * D_OUT };

  const int nblk  = (n + 1023) / 1024;
  const int nblkE = (ne + 4095) / 4096;

  hipMemsetAsync(counts, 0, (size_t)2 * n * 4, stream);
  gemm_kernel<<<dim3((n + 31) / 32, 2), 256, 0, stream>>>(W, bs, bt, n);
  count_kernel<<<dim3((ne + 255) / 256, 2), 256, 0, stream>>>(bs, bt, ne);
  scanA_kernel<<<dim3(nblk, 2), 1024, 0, stream>>>(bs, bt, n);
  scanB_kernel<<<dim3(1, 2), 64, 0, stream>>>(bs, bt, nblk, n);
  scanC_kernel<<<dim3(nblk, 2), 1024, 0, stream>>>(bs, bt, n);
  bin_kernel<<<dim3(nblkE, 2), 256, 0, stream>>>(bs, bt, ne, nb);
  fill2_kernel<<<dim3(nblkE, 2), 256, 0, stream>>>(bs, bt, ne);
  gather_kernel<<<dim3((n + 7) / 8, 2), 256, 0, stream>>>(bs, bt, n);
}

// Round 4
// 295.682 us; speedup vs baseline: 2.2659x; 1.5352x over previous
//
#include <hip/hip_runtime.h>
#include <cstdint>
#include <cstddef>

#define D_IN   256
#define D_OUT  128
#define NB_MAX 256   // row buckets = (n+255)>>8 ; requires n <= 65535 (row/col in 16 bits)

struct Branch {
  const float* X;
  const int*   idx;
  const float* val;
  uint32_t* H;          // bf16x2 packed, 64 words per row
  int*   ptr;           // n+1
  int*   bucketTotal;   // NB_MAX
  int*   bucketBase;    // NB_MAX+1
  int*   bucketCur;     // NB_MAX
  uint64_t* kv2;        // ne: bucket-grouped (val32 | row16 | col16)
  uint64_t* csr_kv;     // ne: (val32 | col)
  float* out;
};

__device__ inline uint32_t pack_bf16_2(float a, float b) {
  uint32_t ua = __float_as_uint(a);
  uint32_t ub = __float_as_uint(b);
  uint32_t ra = (ua + 0x7FFFu + ((ua >> 16) & 1u)) >> 16;   // RNE
  uint32_t rb = ((ub + 0x7FFFu + ((ub >> 16) & 1u)) >> 16) << 16;
  return (ra & 0xFFFFu) | rb;
}

// exclusive prefix over 256 threads (4 waves)
__device__ inline int block_scan256_excl(int v, int tid) {
  int lane = tid & 63, w = tid >> 6;
  int s = v;
  #pragma unroll
  for (int off = 1; off < 64; off <<= 1) {
    int t = __shfl_up(s, off);
    if (lane >= off) s += t;
  }
  __shared__ int wsum[4];
  if (lane == 63) wsum[w] = s;
  __syncthreads();
  int add = 0;
  #pragma unroll
  for (int i = 0; i < 4; ++i) add += (i < w) ? wsum[i] : 0;
  return s + add - v;
}

// ---------------- GEMM: H = X @ W  (fp32 compute, bf16 store) ----------------
__global__ __launch_bounds__(256) void gemm_kernel(const float* __restrict__ W,
                                                   Branch b0, Branch b1, int n_rows) {
  Branch b = blockIdx.y ? b1 : b0;
  __shared__ float sW[64][128];
  __shared__ float sX[32][64];
  const int tid = threadIdx.x;
  const int c4  = (tid & 31) * 4;
  const int rg  = (tid >> 5) * 4;
  const int row0 = blockIdx.x * 32;

  float4 acc[4];
  #pragma unroll
  for (int i = 0; i < 4; ++i) acc[i] = make_float4(0.f, 0.f, 0.f, 0.f);

  for (int k0 = 0; k0 < D_IN; k0 += 64) {
    const float4* Wv  = (const float4*)(W + (size_t)k0 * D_OUT);
    float4* sWv = (float4*)&sW[0][0];
    #pragma unroll
    for (int i = 0; i < 8; ++i) sWv[i * 256 + tid] = Wv[i * 256 + tid];
    float4* sXv = (float4*)&sX[0][0];
    #pragma unroll
    for (int i = 0; i < 2; ++i) {
      int f = i * 256 + tid;
      int r = f >> 4, kk = f & 15;
      int gr = row0 + r; if (gr > n_rows - 1) gr = n_rows - 1;
      sXv[f] = ((const float4*)(b.X + (size_t)gr * D_IN + k0))[kk];
    }
    __syncthreads();
    #pragma unroll 8
    for (int k = 0; k < 64; ++k) {
      float4 w = *(const float4*)&sW[k][c4];
      float x0 = sX[rg + 0][k];
      float x1 = sX[rg + 1][k];
      float x2 = sX[rg + 2][k];
      float x3 = sX[rg + 3][k];
      acc[0].x = fmaf(w.x, x0, acc[0].x); acc[0].y = fmaf(w.y, x0, acc[0].y);
      acc[0].z = fmaf(w.z, x0, acc[0].z); acc[0].w = fmaf(w.w, x0, acc[0].w);
      acc[1].x = fmaf(w.x, x1, acc[1].x); acc[1].y = fmaf(w.y, x1, acc[1].y);
      acc[1].z = fmaf(w.z, x1, acc[1].z); acc[1].w = fmaf(w.w, x1, acc[1].w);
      acc[2].x = fmaf(w.x, x2, acc[2].x); acc[2].y = fmaf(w.y, x2, acc[2].y);
      acc[2].z = fmaf(w.z, x2, acc[2].z); acc[2].w = fmaf(w.w, x2, acc[2].w);
      acc[3].x = fmaf(w.x, x3, acc[3].x); acc[3].y = fmaf(w.y, x3, acc[3].y);
      acc[3].z = fmaf(w.z, x3, acc[3].z); acc[3].w = fmaf(w.w, x3, acc[3].w);
    }
    __syncthreads();
  }
  #pragma unroll
  for (int i = 0; i < 4; ++i) {
    int r = row0 + rg + i;
    if (r < n_rows) {
      uint2 hp;
      hp.x = pack_bf16_2(acc[i].x, acc[i].y);
      hp.y = pack_bf16_2(acc[i].z, acc[i].w);
      *(uint2*)&b.H[(size_t)r * (D_OUT / 2) + (c4 >> 1)] = hp;
    }
  }
}

// ---------------- bucket-level counting (LDS histogram, bucket-granular atomics) ----------------
__global__ __launch_bounds__(256) void bucket_count_kernel(Branch b0, Branch b1, int ne, int nb) {
  Branch b = blockIdx.y ? b1 : b0;
  __shared__ int hist[NB_MAX];
  const int tid = threadIdx.x;
  const int base = blockIdx.x * 4096;
  if (tid < nb) hist[tid] = 0;
  __syncthreads();
  #pragma unroll
  for (int i = 0; i < 16; ++i) {
    int e = base + i * 256 + tid;
    if (e < ne) {
      int r = ((const int2*)b.idx)[e].x;
      atomicAdd(&hist[r >> 8], 1);
    }
  }
  __syncthreads();
  if (tid < nb) {
    int h = hist[tid];
    if (h) atomicAdd(&b.bucketTotal[tid], h);
  }
}

__global__ __launch_bounds__(256) void bucket_scan_kernel(Branch b0, Branch b1, int nb, int n, int ne) {
  Branch b = blockIdx.y ? b1 : b0;
  const int tid = threadIdx.x;
  int v = (tid < nb) ? b.bucketTotal[tid] : 0;
  int excl = block_scan256_excl(v, tid);
  if (tid <= nb) b.bucketBase[tid] = excl;   // bucketBase[nb] == ne
  if (tid < nb)  b.bucketCur[tid]  = excl;
  if (tid == 0)  b.ptr[n] = ne;
}

// ---------------- bin: bucket-grouped scatter ----------------
__global__ __launch_bounds__(256) void bin_kernel(Branch b0, Branch b1, int ne, int nb) {
  Branch b = blockIdx.y ? b1 : b0;
  __shared__ int hist[NB_MAX];
  __shared__ int lcur[NB_MAX];
  __shared__ int gbase[NB_MAX];
  const int tid = threadIdx.x;
  const int base = blockIdx.x * 4096;
  if (tid < nb) hist[tid] = 0;
  __syncthreads();
  uint64_t kv2[16];
  int bkt[16];
  #pragma unroll
  for (int i = 0; i < 16; ++i) {
    int e = base + i * 256 + tid;
    bkt[i] = -1;
    if (e < ne) {
      int2 rc = ((const int2*)b.idx)[e];
      uint32_t v = __float_as_uint(b.val[e]);
      kv2[i] = ((uint64_t)v << 32) | ((uint32_t)rc.x << 16) | (uint32_t)rc.y;
      bkt[i] = rc.x >> 8;
      atomicAdd(&hist[bkt[i]], 1);
    }
  }
  __syncthreads();
  if (tid < nb) {
    int h = hist[tid];
    gbase[tid] = h ? atomicAdd(&b.bucketCur[tid], h) : 0;
    lcur[tid] = 0;
  }
  __syncthreads();
  #pragma unroll
  for (int i = 0; i < 16; ++i) {
    if (bkt[i] >= 0) {
      int dst = gbase[bkt[i]] + atomicAdd(&lcur[bkt[i]], 1);
      b.kv2[dst] = kv2[i];
    }
  }
}

// ---------------- per-bucket CSR finalize: LDS hist + scan + LDS-cursor scatter ----------------
__global__ __launch_bounds__(256) void bucket_csr_kernel(Branch b0, Branch b1, int n) {
  Branch b = blockIdx.y ? b1 : b0;
  const int bkt = blockIdx.x;
  const int tid = threadIdx.x;
  const int beg = b.bucketBase[bkt], end = b.bucketBase[bkt + 1];
  __shared__ int hist[256];
  __shared__ int cur[256];
  hist[tid] = 0;
  __syncthreads();
  for (int e = beg + tid; e < end; e += 256)
    atomicAdd(&hist[(int)((b.kv2[e] >> 16) & 0xFF)], 1);
  __syncthreads();
  int v = hist[tid];
  int excl = block_scan256_excl(v, tid);
  cur[tid] = beg + excl;
  int row = bkt * 256 + tid;
  if (row < n) b.ptr[row] = beg + excl;
  __syncthreads();
  for (int e = beg + tid; e < end; e += 256) {
    uint64_t kv2 = b.kv2[e];
    int r = (int)((kv2 >> 16) & 0xFF);
    int pos = atomicAdd(&cur[r], 1);
    b.csr_kv[pos] = (kv2 & 0xFFFFFFFF00000000ULL) | (uint32_t)(kv2 & 0xFFFF);
  }
}

// ---------------- per-row gather + relu ----------------
__global__ __launch_bounds__(256) void gather_kernel(Branch b0, Branch b1, int n_rows) {
  Branch b = blockIdx.y ? b1 : b0;
  int row = blockIdx.x * 8 + (threadIdx.x >> 5);
  if (row >= n_rows) return;
  int lane2 = (threadIdx.x & 31) * 2;
  int beg = b.ptr[row], end = b.ptr[row + 1];
  float4 acc = make_float4(0.f, 0.f, 0.f, 0.f);

  auto fma_edge = [&](uint64_t kv) {
    int c = (int)(uint32_t)kv;
    float v = __uint_as_float((uint32_t)(kv >> 32));
    uint2 h = *(const uint2*)&b.H[(size_t)c * (D_OUT / 2) + lane2];
    float h0 = __uint_as_float(h.x << 16);
    float h1 = __uint_as_float(h.x & 0xFFFF0000u);
    float h2 = __uint_as_float(h.y << 16);
    float h3 = __uint_as_float(h.y & 0xFFFF0000u);
    acc.x = fmaf(h0, v, acc.x); acc.y = fmaf(h1, v, acc.y);
    acc.z = fmaf(h2, v, acc.z); acc.w = fmaf(h3, v, acc.w);
  };

  int e = beg;
  for (; e + 4 <= end; e += 4) {
    uint64_t kA = b.csr_kv[e + 0], kB = b.csr_kv[e + 1];
    uint64_t kC = b.csr_kv[e + 2], kD = b.csr_kv[e + 3];
    fma_edge(kA); fma_edge(kB); fma_edge(kC); fma_edge(kD);
  }
  for (; e < end; ++e) fma_edge(b.csr_kv[e]);

  float4 o;
  o.x = fmaxf(acc.x, 0.f); o.y = fmaxf(acc.y, 0.f);
  o.z = fmaxf(acc.z, 0.f); o.w = fmaxf(acc.w, 0.f);
  *(float4*)&b.out[(size_t)row * D_OUT + (threadIdx.x & 31) * 4] = o;
}

extern "C" void kernel_launch(void* const* d_in, const int* in_sizes, int n_in,
                              void* d_out, int out_size, void* d_ws, size_t ws_size,
                              hipStream_t stream) {
  const float* inp_s = (const float*)d_in[0];
  const float* inp_t = (const float*)d_in[1];
  const int*   idx_s = (const int*)d_in[2];
  const float* val_s = (const float*)d_in[3];
  const int*   idx_t = (const int*)d_in[4];
  const float* val_t = (const float*)d_in[5];
  const float* W     = (const float*)d_in[6];
  float* out = (float*)d_out;

  const int n  = in_sizes[0] / D_IN;   // 50000
  const int ne = in_sizes[3];          // 1600000
  const int nb = (n + 255) >> 8;       // 196

  char* p = (char*)d_ws;
  auto alloc = [&](size_t bytes) -> char* {
    char* r = p;
    p += (bytes + 255) & ~(size_t)255;
    return r;
  };
  uint32_t* H_s    = (uint32_t*)alloc((size_t)n * (D_OUT / 2) * 4);
  uint32_t* H_t    = (uint32_t*)alloc((size_t)n * (D_OUT / 2) * 4);
  int* ptr_s       = (int*)alloc((size_t)(n + 1) * 4);
  int* ptr_t       = (int*)alloc((size_t)(n + 1) * 4);
  int* btotal      = (int*)alloc((size_t)2 * NB_MAX * 4);   // one memset covers both
  int* btotal_s    = btotal;
  int* btotal_t    = btotal + NB_MAX;
  int* bbase_s     = (int*)alloc((size_t)(NB_MAX + 1) * 4);
  int* bbase_t     = (int*)alloc((size_t)(NB_MAX + 1) * 4);
  int* bcur_s      = (int*)alloc(NB_MAX * 4);
  int* bcur_t      = (int*)alloc(NB_MAX * 4);
  uint64_t* kv2_s  = (uint64_t*)alloc((size_t)ne * 8);
  uint64_t* kv2_t  = (uint64_t*)alloc((size_t)ne * 8);
  uint64_t* kv_s   = (uint64_t*)alloc((size_t)ne * 8);
  uint64_t* kv_t   = (uint64_t*)alloc((size_t)ne * 8);

  Branch bs = { inp_s, idx_s, val_s, H_s, ptr_s, btotal_s, bbase_s, bcur_s, kv2_s, kv_s, out };
  Branch bt = { inp_t, idx_t, val_t, H_t, ptr_t, btotal_t, bbase_t, bcur_t, kv2_t, kv_t,
                out + (size_t)n * D_OUT };

  const int nblkE = (ne + 4095) / 4096;

  hipMemsetAsync(btotal, 0, (size_t)2 * NB_MAX * 4, stream);
  gemm_kernel<<<dim3((n + 31) / 32, 2), 256, 0, stream>>>(W, bs, bt, n);
  bucket_count_kernel<<<dim3(nblkE, 2), 256, 0, stream>>>(bs, bt, ne, nb);
  bucket_scan_kernel<<<dim3(1, 2), 256, 0, stream>>>(bs, bt, nb, n, ne);
  bin_kernel<<<dim3(nblkE, 2), 256, 0, stream>>>(bs, bt, ne, nb);
  bucket_csr_kernel<<<dim3(nb, 2), 256, 0, stream>>>(bs, bt, n);
  gather_kernel<<<dim3((n + 7) / 8, 2), 256, 0, stream>>>(bs, bt, n);
}

// Round 5
// 273.866 us; speedup vs baseline: 2.4464x; 1.0797x over previous
//
#include <hip/hip_runtime.h>
#include <cstdint>
#include <cstddef>

#define D_IN   256
#define D_OUT  128
#define NB_MAX 256   // row buckets = (n+255)>>8 ; requires n <= 65535 (row/col in 16 bits)

typedef short bf16x8 __attribute__((ext_vector_type(8)));
typedef float f32x4  __attribute__((ext_vector_type(4)));

union Frag { bf16x8 v; uint32_t u[4]; };

struct Branch {
  const float* X;
  const int*   idx;
  const float* val;
  uint32_t* H;          // bf16x2 packed, 64 words per row
  int*   ptr;           // n+1
  int*   bucketTotal;   // NB_MAX
  int*   bucketBase;    // NB_MAX+1
  int*   bucketCur;     // NB_MAX
  uint64_t* kv2;        // ne: bucket-grouped (val32 | row16 | col16)
  uint64_t* csr_kv;     // ne: (val32 | col)
  float* out;
};

__device__ inline uint32_t cvt_pk_bf16(float lo, float hi) {
  uint32_t r;
  asm("v_cvt_pk_bf16_f32 %0, %1, %2" : "=v"(r) : "v"(lo), "v"(hi));
  return r;
}

// exclusive prefix over 256 threads (4 waves)
__device__ inline int block_scan256_excl(int v, int tid) {
  int lane = tid & 63, w = tid >> 6;
  int s = v;
  #pragma unroll
  for (int off = 1; off < 64; off <<= 1) {
    int t = __shfl_up(s, off);
    if (lane >= off) s += t;
  }
  __shared__ int wsum[4];
  if (lane == 63) wsum[w] = s;
  __syncthreads();
  int add = 0;
  #pragma unroll
  for (int i = 0; i < 4; ++i) add += (i < w) ? wsum[i] : 0;
  return s + add - v;
}

// ---------------- W prep: W[256][128] fp32 -> W^T[128][256] bf16 (RNE) ----------------
__global__ __launch_bounds__(256) void wprep_kernel(const float* __restrict__ W,
                                                    uint16_t* __restrict__ WT) {
  int n = blockIdx.x;    // 0..127
  int k = threadIdx.x;   // 0..255
  uint32_t u = __float_as_uint(W[k * 128 + n]);
  WT[n * 256 + k] = (uint16_t)((u + 0x7FFFu + ((u >> 16) & 1u)) >> 16);
}

// ---------------- GEMM: H = X @ W  (bf16 MFMA, fp32 acc, bf16 store) ----------------
// block 256 = 4 waves; each wave computes 32 rows x 128 cols; block = 128 rows.
__global__ __launch_bounds__(256, 2) void gemm_mfma_kernel(const uint16_t* __restrict__ WT,
                                                           Branch b0, Branch b1, int n_rows) {
  Branch b = blockIdx.y ? b1 : b0;
  const int tid = threadIdx.x;
  const int w = tid >> 6;
  const int l = tid & 63;
  const int c = l & 15;
  const int g = l >> 4;
  const int row0 = blockIdx.x * 128 + w * 32;

  __shared__ uint16_t sStg[4][32][136];

  f32x4 acc[2][8];
  #pragma unroll
  for (int i = 0; i < 2; ++i)
    #pragma unroll
    for (int j = 0; j < 8; ++j) acc[i][j] = (f32x4){0.f, 0.f, 0.f, 0.f};

  int r0 = row0 + c;      if (r0 > n_rows - 1) r0 = n_rows - 1;
  int r1 = row0 + 16 + c; if (r1 > n_rows - 1) r1 = n_rows - 1;
  const float4* X0 = (const float4*)(b.X + (size_t)r0 * D_IN);
  const float4* X1 = (const float4*)(b.X + (size_t)r1 * D_IN);

  #pragma unroll
  for (int ks = 0; ks < 8; ++ks) {
    const int k4 = ks * 8;  // float4 index of k0 = ks*32
    // A frags: lane reads k = k0+4g..+3 and k0+16+4g..+3 (fp32), cvt to bf16
    float4 a0 = X0[k4 + g], a0b = X0[k4 + 4 + g];
    float4 a1 = X1[k4 + g], a1b = X1[k4 + 4 + g];
    Frag A0, A1;
    A0.u[0] = cvt_pk_bf16(a0.x, a0.y);   A0.u[1] = cvt_pk_bf16(a0.z, a0.w);
    A0.u[2] = cvt_pk_bf16(a0b.x, a0b.y); A0.u[3] = cvt_pk_bf16(a0b.z, a0b.w);
    A1.u[0] = cvt_pk_bf16(a1.x, a1.y);   A1.u[1] = cvt_pk_bf16(a1.z, a1.w);
    A1.u[2] = cvt_pk_bf16(a1b.x, a1b.y); A1.u[3] = cvt_pk_bf16(a1b.z, a1b.w);
    #pragma unroll
    for (int nf = 0; nf < 8; ++nf) {
      const uint2* Wp = (const uint2*)(WT + ((size_t)(nf * 16 + c) << 8));
      uint2 wa = Wp[k4 + g];
      uint2 wb = Wp[k4 + 4 + g];
      Frag B;
      B.u[0] = wa.x; B.u[1] = wa.y; B.u[2] = wb.x; B.u[3] = wb.y;
      acc[0][nf] = __builtin_amdgcn_mfma_f32_16x16x32_bf16(A0.v, B.v, acc[0][nf], 0, 0, 0);
      acc[1][nf] = __builtin_amdgcn_mfma_f32_16x16x32_bf16(A1.v, B.v, acc[1][nf], 0, 0, 0);
    }
  }

  // epilogue: pair cols via shfl_xor(1), pack bf16x2, stage in LDS, wide store
  #pragma unroll
  for (int rf = 0; rf < 2; ++rf)
    #pragma unroll
    for (int nf = 0; nf < 8; ++nf)
      #pragma unroll
      for (int r = 0; r < 4; ++r) {
        float v = acc[rf][nf][r];
        float o = __shfl_xor(v, 1);
        if (!(l & 1)) {
          uint32_t pk = cvt_pk_bf16(v, o);
          int rowl = rf * 16 + g * 4 + r;
          int col  = nf * 16 + c;
          *(uint32_t*)&sStg[w][rowl][col] = pk;
        }
      }
  __syncthreads();
  {
    int rl = l >> 1, half = l & 1;
    int row_g = row0 + rl;
    if (row_g < n_rows) {
      uint16_t* Hrow = (uint16_t*)b.H + (size_t)row_g * 128 + half * 64;
      #pragma unroll
      for (int i = 0; i < 8; ++i) {
        uint4 q = *(const uint4*)&sStg[w][rl][half * 64 + i * 8];
        *(uint4*)(Hrow + i * 8) = q;
      }
    }
  }
}

// ---------------- bucket-level counting ----------------
__global__ __launch_bounds__(256) void bucket_count_kernel(Branch b0, Branch b1, int ne, int nb) {
  Branch b = blockIdx.y ? b1 : b0;
  __shared__ int hist[NB_MAX];
  const int tid = threadIdx.x;
  const int base = blockIdx.x * 4096;
  if (tid < nb) hist[tid] = 0;
  __syncthreads();
  #pragma unroll
  for (int i = 0; i < 16; ++i) {
    int e = base + i * 256 + tid;
    if (e < ne) {
      int r = ((const int2*)b.idx)[e].x;
      atomicAdd(&hist[r >> 8], 1);
    }
  }
  __syncthreads();
  if (tid < nb) {
    int h = hist[tid];
    if (h) atomicAdd(&b.bucketTotal[tid], h);
  }
}

__global__ __launch_bounds__(256) void bucket_scan_kernel(Branch b0, Branch b1, int nb, int n, int ne) {
  Branch b = blockIdx.y ? b1 : b0;
  const int tid = threadIdx.x;
  int v = (tid < nb) ? b.bucketTotal[tid] : 0;
  int excl = block_scan256_excl(v, tid);
  if (tid <= nb) b.bucketBase[tid] = excl;
  if (tid < nb)  b.bucketCur[tid]  = excl;
  if (tid == 0)  b.ptr[n] = ne;
}

// ---------------- bin: bucket-grouped scatter ----------------
__global__ __launch_bounds__(256) void bin_kernel(Branch b0, Branch b1, int ne, int nb) {
  Branch b = blockIdx.y ? b1 : b0;
  __shared__ int hist[NB_MAX];
  __shared__ int lcur[NB_MAX];
  __shared__ int gbase[NB_MAX];
  const int tid = threadIdx.x;
  const int base = blockIdx.x * 4096;
  if (tid < nb) hist[tid] = 0;
  __syncthreads();
  uint64_t kv2[16];
  int bkt[16];
  #pragma unroll
  for (int i = 0; i < 16; ++i) {
    int e = base + i * 256 + tid;
    bkt[i] = -1;
    if (e < ne) {
      int2 rc = ((const int2*)b.idx)[e];
      uint32_t v = __float_as_uint(b.val[e]);
      kv2[i] = ((uint64_t)v << 32) | ((uint32_t)rc.x << 16) | (uint32_t)rc.y;
      bkt[i] = rc.x >> 8;
      atomicAdd(&hist[bkt[i]], 1);
    }
  }
  __syncthreads();
  if (tid < nb) {
    int h = hist[tid];
    gbase[tid] = h ? atomicAdd(&b.bucketCur[tid], h) : 0;
    lcur[tid] = 0;
  }
  __syncthreads();
  #pragma unroll
  for (int i = 0; i < 16; ++i) {
    if (bkt[i] >= 0) {
      int dst = gbase[bkt[i]] + atomicAdd(&lcur[bkt[i]], 1);
      b.kv2[dst] = kv2[i];
    }
  }
}

// ---------------- per-bucket CSR finalize ----------------
__global__ __launch_bounds__(256) void bucket_csr_kernel(Branch b0, Branch b1, int n) {
  Branch b = blockIdx.y ? b1 : b0;
  const int bkt = blockIdx.x;
  const int tid = threadIdx.x;
  const int beg = b.bucketBase[bkt], end = b.bucketBase[bkt + 1];
  __shared__ int hist[256];
  __shared__ int cur[256];
  hist[tid] = 0;
  __syncthreads();
  for (int e = beg + tid; e < end; e += 256)
    atomicAdd(&hist[(int)((b.kv2[e] >> 16) & 0xFF)], 1);
  __syncthreads();
  int v = hist[tid];
  int excl = block_scan256_excl(v, tid);
  cur[tid] = beg + excl;
  int row = bkt * 256 + tid;
  if (row < n) b.ptr[row] = beg + excl;
  __syncthreads();
  for (int e = beg + tid; e < end; e += 256) {
    uint64_t kv2 = b.kv2[e];
    int r = (int)((kv2 >> 16) & 0xFF);
    int pos = atomicAdd(&cur[r], 1);
    b.csr_kv[pos] = (kv2 & 0xFFFFFFFF00000000ULL) | (uint32_t)(kv2 & 0xFFFF);
  }
}

// ---------------- per-row gather + relu ----------------
__global__ __launch_bounds__(256) void gather_kernel(Branch b0, Branch b1, int n_rows) {
  Branch b = blockIdx.y ? b1 : b0;
  int row = blockIdx.x * 8 + (threadIdx.x >> 5);
  if (row >= n_rows) return;
  int lane2 = (threadIdx.x & 31) * 2;
  int beg = b.ptr[row], end = b.ptr[row + 1];
  float4 acc = make_float4(0.f, 0.f, 0.f, 0.f);

  auto fma_edge = [&](uint64_t kv) {
    int c = (int)(uint32_t)kv;
    float v = __uint_as_float((uint32_t)(kv >> 32));
    uint2 h = *(const uint2*)&b.H[(size_t)c * (D_OUT / 2) + lane2];
    float h0 = __uint_as_float(h.x << 16);
    float h1 = __uint_as_float(h.x & 0xFFFF0000u);
    float h2 = __uint_as_float(h.y << 16);
    float h3 = __uint_as_float(h.y & 0xFFFF0000u);
    acc.x = fmaf(h0, v, acc.x); acc.y = fmaf(h1, v, acc.y);
    acc.z = fmaf(h2, v, acc.z); acc.w = fmaf(h3, v, acc.w);
  };

  int e = beg;
  for (; e + 4 <= end; e += 4) {
    uint64_t kA = b.csr_kv[e + 0], kB = b.csr_kv[e + 1];
    uint64_t kC = b.csr_kv[e + 2], kD = b.csr_kv[e + 3];
    fma_edge(kA); fma_edge(kB); fma_edge(kC); fma_edge(kD);
  }
  for (; e < end; ++e) fma_edge(b.csr_kv[e]);

  float4 o;
  o.x = fmaxf(acc.x, 0.f); o.y = fmaxf(acc.y, 0.f);
  o.z = fmaxf(acc.z, 0.f); o.w = fmaxf(acc.w, 0.f);
  *(float4*)&b.out[(size_t)row * D_OUT + (threadIdx.x & 31) * 4] = o;
}

extern "C" void kernel_launch(void* const* d_in, const int* in_sizes, int n_in,
                              void* d_out, int out_size, void* d_ws, size_t ws_size,
                              hipStream_t stream) {
  const float* inp_s = (const float*)d_in[0];
  const float* inp_t = (const float*)d_in[1];
  const int*   idx_s = (const int*)d_in[2];
  const float* val_s = (const float*)d_in[3];
  const int*   idx_t = (const int*)d_in[4];
  const float* val_t = (const float*)d_in[5];
  const float* W     = (const float*)d_in[6];
  float* out = (float*)d_out;

  const int n  = in_sizes[0] / D_IN;   // 50000
  const int ne = in_sizes[3];          // 1600000
  const int nb = (n + 255) >> 8;       // 196

  char* p = (char*)d_ws;
  auto alloc = [&](size_t bytes) -> char* {
    char* r = p;
    p += (bytes + 255) & ~(size_t)255;
    return r;
  };
  uint32_t* H_s    = (uint32_t*)alloc((size_t)n * (D_OUT / 2) * 4);
  uint32_t* H_t    = (uint32_t*)alloc((size_t)n * (D_OUT / 2) * 4);
  uint16_t* WT     = (uint16_t*)alloc((size_t)128 * 256 * 2);
  int* ptr_s       = (int*)alloc((size_t)(n + 1) * 4);
  int* ptr_t       = (int*)alloc((size_t)(n + 1) * 4);
  int* btotal      = (int*)alloc((size_t)2 * NB_MAX * 4);
  int* btotal_s    = btotal;
  int* btotal_t    = btotal + NB_MAX;
  int* bbase_s     = (int*)alloc((size_t)(NB_MAX + 1) * 4);
  int* bbase_t     = (int*)alloc((size_t)(NB_MAX + 1) * 4);
  int* bcur_s      = (int*)alloc(NB_MAX * 4);
  int* bcur_t      = (int*)alloc(NB_MAX * 4);
  uint64_t* kv2_s  = (uint64_t*)alloc((size_t)ne * 8);
  uint64_t* kv2_t  = (uint64_t*)alloc((size_t)ne * 8);
  uint64_t* kv_s   = (uint64_t*)alloc((size_t)ne * 8);
  uint64_t* kv_t   = (uint64_t*)alloc((size_t)ne * 8);

  Branch bs = { inp_s, idx_s, val_s, H_s, ptr_s, btotal_s, bbase_s, bcur_s, kv2_s, kv_s, out };
  Branch bt = { inp_t, idx_t, val_t, H_t, ptr_t, btotal_t, bbase_t, bcur_t, kv2_t, kv_t,
                out + (size_t)n * D_OUT };

  const int nblkE = (ne + 4095) / 4096;

  hipMemsetAsync(btotal, 0, (size_t)2 * NB_MAX * 4, stream);
  wprep_kernel<<<dim3(128), 256, 0, stream>>>(W, WT);
  gemm_mfma_kernel<<<dim3((n + 127) / 128, 2), 256, 0, stream>>>(WT, bs, bt, n);
  bucket_count_kernel<<<dim3(nblkE, 2), 256, 0, stream>>>(bs, bt, ne, nb);
  bucket_scan_kernel<<<dim3(1, 2), 256, 0, stream>>>(bs, bt, nb, n, ne);
  bin_kernel<<<dim3(nblkE, 2), 256, 0, stream>>>(bs, bt, ne, nb);
  bucket_csr_kernel<<<dim3(nb, 2), 256, 0, stream>>>(bs, bt, n);
  gather_kernel<<<dim3((n + 7) / 8, 2), 256, 0, stream>>>(bs, bt, n);
}